// Round 13
// baseline (141.206 us; speedup 1.0000x reference)
//
#include <hip/hip_runtime.h>

#define NN 50000
#define NE 800000
#define NBLK 196   // bucket count (256 nodes/bucket); also edge-chunk blocks
#define CAP 5120   // padded slots per bucket (mean 4082, +16 sigma)

typedef _Float16 half8 __attribute__((ext_vector_type(8)));
typedef _Float16 half4 __attribute__((ext_vector_type(4)));
typedef float f32x4v __attribute__((ext_vector_type(4)));

// =================== K_A: padded partition pass 1 + prep1 + w1 pack ===================
__launch_bounds__(256)
__global__ void k_A(const int* __restrict__ srcv, const int* __restrict__ dstv,
                    int* __restrict__ bcur, unsigned int* __restrict__ epk2,
                    const float* __restrict__ wd3, const float* __restrict__ wf,
                    const float* __restrict__ w2, const float* __restrict__ fw2,
                    const float* __restrict__ w3, const float* __restrict__ fw3,
                    const float* __restrict__ b1, const float* __restrict__ fw1,
                    const float* __restrict__ fb1,
                    const float* __restrict__ b2, const float* __restrict__ fb2,
                    const float* __restrict__ b3, const float* __restrict__ fb3,
                    float* __restrict__ G,
                    float* __restrict__ Wc2, float* __restrict__ Wc3,
                    float* __restrict__ bc1, float* __restrict__ bc2,
                    float* __restrict__ bc3,
                    const float* __restrict__ w1, _Float16* __restrict__ W1pk) {
  __shared__ int cnt[256];
  __shared__ int base[256];
  int t = threadIdx.x;
  int b = blockIdx.x;
  if (b < NBLK) {  // ---- part1 (padded buckets, no prior histogram) ----
    int e0 = b * 4096;
    cnt[t] = 0;
    __syncthreads();
    unsigned int pk[16];
    int lo[16], bk[16];
    bool ok[16];
#pragma unroll
    for (int i = 0; i < 16; ++i) {
      int e = e0 + i * 256 + t;
      ok[i] = (e < NE);
      if (ok[i]) {
        int s = srcv[e], d = dstv[e];
        bk[i] = d >> 8;
        pk[i] = (unsigned int)s | ((unsigned int)(d & 255) << 16);
        lo[i] = atomicAdd(&cnt[bk[i]], 1);
      }
    }
    __syncthreads();
    int c = cnt[t];
    if (c > 0) base[t] = atomicAdd(&bcur[t], c);
    __syncthreads();
#pragma unroll
    for (int i = 0; i < 16; ++i)
      if (ok[i]) epk2[(size_t)bk[i] * CAP + base[bk[i]] + lo[i]] = pk[i];
    return;
  }
  if (b < NBLK + 105) {  // ---- prep1: G + Wc2/Wc3/bc1/bc2/bc3 ----
    int id = (b - NBLK) * 256 + t;
    if (id < 16384) {                      // G[c*4+l, k]
      int k = id & 127, r = id >> 7;
      int c = r >> 2, l = r & 3;
      float s = 0.f;
      for (int o = 0; o < 32; ++o) {
        s = fmaf(wd3[c * 64 + o * 2 + 0], wf[(o * 8 + 2 * l + 0) * 128 + k], s);
        s = fmaf(wd3[c * 64 + o * 2 + 1], wf[(o * 8 + 2 * l + 1) * 128 + k], s);
      }
      G[r * 128 + k] = s;
      return;
    }
    int id2 = id - 16384;
    if (id2 < 2048) {                      // Wc2 [32,64]
      int c = id2 >> 6, k = id2 & 63;
      float s = 0.f;
      for (int j = 0; j < 64; ++j) s = fmaf(w2[c * 64 + j], fw2[j * 64 + k], s);
      Wc2[id2] = s;
    } else if (id2 < 10240) {              // Wc3 [64,128]
      int idx = id2 - 2048;
      int c = idx >> 7, k = idx & 127;
      float s = 0.f;
      for (int j = 0; j < 128; ++j) s = fmaf(w3[c * 128 + j], fw3[j * 128 + k], s);
      Wc3[idx] = s;
    } else if (id2 < 10272) {              // bc1 [32]
      int k = id2 - 10240;
      float s = fb1[k];
      for (int j = 0; j < 32; ++j) s = fmaf(b1[j], fw1[j * 32 + k], s);
      bc1[k] = s;
    } else if (id2 < 10336) {              // bc2 [64]
      int k = id2 - 10272;
      float s = fb2[k];
      for (int j = 0; j < 64; ++j) s = fmaf(b2[j], fw2[j * 64 + k], s);
      bc2[k] = s;
    } else if (id2 < 10464) {              // bc3 [128]
      int k = id2 - 10336;
      float s = fb3[k];
      for (int j = 0; j < 128; ++j) s = fmaf(b3[j], fw3[j * 128 + k], s);
      bc3[k] = s;
    }
    return;
  }
  // ---- pack w1 [128][32] fragments: frag (kb,nb) kb<4, nb<2 ----
#pragma unroll
  for (int it = 0; it < 2; ++it) {
    int id = t + it * 256;
    int l = id & 63, f = id >> 6;
    int kb = f >> 1, nb = f & 1;
    int kbase = kb * 32 + ((l >> 4) << 3);
    int col = nb * 16 + (l & 15);
#pragma unroll
    for (int j = 0; j < 8; ++j)
      W1pk[id * 8 + j] = (_Float16)w1[(kbase + j) * 32 + col];
  }
}

// ====== K_B: pass 2 (per-node degree + local scan + place, padded) + prep_HA1 ======
__launch_bounds__(256)
__global__ void k_B(const unsigned int* __restrict__ epk2, const int* __restrict__ bcur,
                    int* __restrict__ row_start, int* __restrict__ bend,
                    float* __restrict__ dinv, float* __restrict__ rdinv,
                    unsigned short* __restrict__ esrc,
                    const float* __restrict__ wd2, const float* __restrict__ G,
                    const float* __restrict__ ws2,
                    float* __restrict__ Hm, float* __restrict__ A1) {
  int t = threadIdx.x;
  int b = blockIdx.x;
  if (b < NBLK) {  // ---- part2 ----
    __shared__ int cnt[256];
    __shared__ int cur[256];
    __shared__ int ss[256];
    int rs0 = b * CAP;
    int count = bcur[b];
    int rs1 = rs0 + count;
    cnt[t] = 0;
    __syncthreads();
    for (int i = rs0 + t; i < rs1; i += 256) {
      unsigned int p = epk2[i];
      atomicAdd(&cnt[(p >> 16) & 255], 1);
    }
    __syncthreads();
    int d = cnt[t];
    ss[t] = d;
    __syncthreads();
    for (int off = 1; off < 256; off <<= 1) {
      int v = (t >= off) ? ss[t - off] : 0;
      __syncthreads();
      ss[t] += v;
      __syncthreads();
    }
    int rs = rs0 + ss[t] - d;
    int node = b * 256 + t;
    if (node < NN) {
      row_start[node] = rs;
      float df = (float)d + 2.0f;
      dinv[node] = rsqrtf(df);
      rdinv[node] = sqrtf(df);
    }
    if (t == 0) bend[b] = rs1;
    if (b == 0 && t == 0) row_start[NN] = NBLK * CAP;
    cur[t] = rs;
    __syncthreads();
    for (int i = rs0 + t; i < rs1; i += 256) {
      unsigned int p = epk2[i];
      int dl = (p >> 16) & 255;
      int tgt = atomicAdd(&cur[dl], 1);
      esrc[tgt] = (unsigned short)(p & 0xFFFFu);
    }
    return;
  }
  int id = (b - NBLK) * 256 + t;
  if (id < 16384) {
    int k = id & 127, r = id >> 7;
    int c = r >> 1, l = r & 1;
    float s = 0.f;
    for (int o = 0; o < 32; ++o) {
      s = fmaf(wd2[c * 64 + o * 2 + 0], G[(o * 4 + 2 * l + 0) * 128 + k], s);
      s = fmaf(wd2[c * 64 + o * 2 + 1], G[(o * 4 + 2 * l + 1) * 128 + k], s);
    }
    Hm[r * 128 + k] = s;
  } else if (id < 16384 + 4096) {
    int idx = id - 16384;
    int k = idx & 127, c = idx >> 7;   // c < 32
    float s = 0.f;
    for (int o = 0; o < 32; ++o) {
      float g = G[(4 * o) * 128 + k] + G[(4 * o + 1) * 128 + k] +
                G[(4 * o + 2) * 128 + k] + G[(4 * o + 3) * 128 + k];
      s = fmaf(ws2[c * 32 + o], g, s);
    }
    A1[c * 128 + k] = s;
  }
}

// ---- convert 8 f32 -> half8 fragment ----
__device__ inline half8 cvt8f(const float* __restrict__ p) {
  float4 u = *reinterpret_cast<const float4*>(p);
  float4 v = *reinterpret_cast<const float4*>(p + 4);
  half8 a;
  a[0] = (_Float16)u.x; a[1] = (_Float16)u.y; a[2] = (_Float16)u.z; a[3] = (_Float16)u.w;
  a[4] = (_Float16)v.x; a[5] = (_Float16)v.y; a[6] = (_Float16)v.z; a[7] = (_Float16)v.w;
  return a;
}

// ============ K_C: layer-1 MFMA (h1' = dinv*(x@w1) -> f16) + prep_A32c0 ============
#define NG1 782  // (NN+63)/64
__launch_bounds__(256)
__global__ void k_C(const float* __restrict__ X, const half8* __restrict__ W1pk,
                    const float* __restrict__ dinv, _Float16* __restrict__ Yh,
                    const float* __restrict__ wd1, const float* __restrict__ ws1,
                    const float* __restrict__ Hm, const float* __restrict__ G,
                    const float* __restrict__ wf,
                    const float* __restrict__ bd1, const float* __restrict__ bs1,
                    const float* __restrict__ bd2, const float* __restrict__ bs2,
                    const float* __restrict__ bd3, const float* __restrict__ bf,
                    float* __restrict__ A3, float* __restrict__ A2,
                    float* __restrict__ c0) {
  int t = threadIdx.x;
  int b = blockIdx.x;
  if (b < NG1) {  // ---- gemm1m ----
    int w = t >> 6, l = t & 63;
    int m16 = l & 15, g = l >> 4;
    int n0 = b * 64 + w * 16;
    int nrow = n0 + m16;
    f32x4v acc[2];
    acc[0] = (f32x4v){0.f, 0.f, 0.f, 0.f};
    acc[1] = (f32x4v){0.f, 0.f, 0.f, 0.f};
#pragma unroll
    for (int kb = 0; kb < 4; ++kb) {
      half8 a = (half8)(_Float16)0.f;
      if (nrow < NN) a = cvt8f(X + (size_t)nrow * 128 + kb * 32 + g * 8);
#pragma unroll
      for (int nb = 0; nb < 2; ++nb)
        acc[nb] = __builtin_amdgcn_mfma_f32_16x16x32_f16(a, W1pk[(kb * 2 + nb) * 64 + l],
                                                         acc[nb], 0, 0, 0);
    }
#pragma unroll
    for (int nb = 0; nb < 2; ++nb)
#pragma unroll
      for (int r = 0; r < 4; ++r) {
        int n = n0 + g * 4 + r;
        if (n < NN)
          Yh[(size_t)n * 32 + nb * 16 + m16] = (_Float16)(dinv[n] * acc[nb][r]);
      }
    return;
  }
  int id = (b - NG1) * 256 + t;
  if (id < 16384) {
    int k = id & 127, c = id >> 7;
    float s = 0.f;
    for (int j = 0; j < 128; ++j) s = fmaf(wd1[c * 128 + j], Hm[j * 128 + k], s);
    A3[c * 128 + k] = s;
  } else if (id < 16384 + 8192) {
    int idx = id - 16384;
    int k = idx & 127, c = idx >> 7;   // c < 64
    float s = 0.f;
    for (int o = 0; o < 64; ++o)
      s = fmaf(ws1[c * 64 + o], Hm[(2 * o) * 128 + k] + Hm[(2 * o + 1) * 128 + k], s);
    A2[c * 128 + k] = s;
  } else if (id < 16384 + 8192 + 128) {
    int k = id - 16384 - 8192;
    float s = bf[k];
    for (int o = 0; o < 64; ++o) {
      float bb = bd1[o] + bs1[o];
      s = fmaf(bb, Hm[(o * 2) * 128 + k] + Hm[(o * 2 + 1) * 128 + k], s);
    }
    for (int o = 0; o < 32; ++o) {
      float bb = bd2[o] + bs2[o];
      float g = G[(o * 4) * 128 + k] + G[(o * 4 + 1) * 128 + k] +
                G[(o * 4 + 2) * 128 + k] + G[(o * 4 + 3) * 128 + k];
      s = fmaf(bb, g, s);
    }
    for (int o = 0; o < 32; ++o) {
      float w8 = 0.f;
      for (int j = 0; j < 8; ++j) w8 += wf[(o * 8 + j) * 128 + k];
      s = fmaf(bd3[o], w8, s);
    }
    c0[k] = s;
  }
}

// ====== K_D: fuse1 (8-way gather h1 + GEMM 32->32 + relu -> x1 f16) + B-frag pack ======
#define NF1 6250  // NN/8
__launch_bounds__(256)
__global__ void k_D(const _Float16* __restrict__ H, const unsigned short* __restrict__ esrc,
                    const int* __restrict__ row_start, const int* __restrict__ bend,
                    const float* __restrict__ dinv,
                    const float* __restrict__ W, const float* __restrict__ bias,
                    _Float16* __restrict__ Y,
                    const float* __restrict__ Wc3, const float* __restrict__ Acat,
                    _Float16* __restrict__ W3pk, _Float16* __restrict__ Apk) {
  int t = threadIdx.x;
  int b = blockIdx.x;
  if (b < NF1) {  // ---- fuse1: 8 nodes/block, 32 lanes/node (fg<4 half8, way<8) ----
    __shared__ float sZT[32][9];
    __shared__ float sW[32 * 32];
    int n0 = b * 8;
    {
      int kr = t >> 3, c4 = (t & 7) * 4;
      *reinterpret_cast<float4*>(&sW[kr * 32 + c4]) =
          *reinterpret_cast<const float4*>(&W[kr * 32 + c4]);
    }
    int node = t >> 5, sub = t & 31, fg = sub & 3, way = sub >> 2;
    int n = n0 + node;
    const half8* H8 = reinterpret_cast<const half8*>(H);
    float acc[8];
#pragma unroll
    for (int j = 0; j < 8; ++j) acc[j] = 0.f;
    if (way == 0) {
      half8 h = H8[(size_t)n * 4 + fg];
#pragma unroll
      for (int j = 0; j < 8; ++j) acc[j] = 2.f * (float)h[j];
    }
    int end = min(row_start[n + 1], bend[n >> 8]);
    int i = row_start[n] + way;
    for (; i + 8 < end; i += 16) {
      int s0 = esrc[i], s1 = esrc[i + 8];
      half8 a = H8[(size_t)s0 * 4 + fg];
      half8 bb = H8[(size_t)s1 * 4 + fg];
#pragma unroll
      for (int j = 0; j < 8; ++j) acc[j] += (float)a[j] + (float)bb[j];
    }
    for (; i < end; i += 8) {
      int s = esrc[i];
      half8 a = H8[(size_t)s * 4 + fg];
#pragma unroll
      for (int j = 0; j < 8; ++j) acc[j] += (float)a[j];
    }
#pragma unroll
    for (int j = 0; j < 8; ++j) {
      acc[j] += __shfl_xor(acc[j], 4);
      acc[j] += __shfl_xor(acc[j], 8);
      acc[j] += __shfl_xor(acc[j], 16);
    }
    if (way == 0) {
      float dv = dinv[n];
#pragma unroll
      for (int j = 0; j < 8; ++j) sZT[fg * 8 + j][node] = dv * acc[j];
    }
    __syncthreads();
    int nd = t >> 5, col = t & 31;
    float a = bias[col];
#pragma unroll
    for (int k = 0; k < 32; ++k) a = fmaf(sZT[k][nd], sW[k * 32 + col], a);
    Y[(size_t)(n0 + nd) * 32 + col] = (_Float16)(dinv[n0 + nd] * fmaxf(a, 0.f));
    return;
  }
  int id = (b - NF1) * 256 + t;
  if (id < 1024) {
    int l = id & 63, nb = (id >> 6) & 7, kb = id >> 9;
    int kbase = kb * 32 + ((l >> 4) << 3);
    int col = nb * 16 + (l & 15);
#pragma unroll
    for (int j = 0; j < 8; ++j)
      W3pk[id * 8 + j] = (_Float16)Wc3[(kbase + j) * 128 + col];
  } else if (id < 1024 + 3584) {
    int idx = id - 1024;
    int l = idx & 63, nb = (idx >> 6) & 7, kb = idx >> 9;
    int kbase = kb * 32 + ((l >> 4) << 3);
    int col = nb * 16 + (l & 15);
#pragma unroll
    for (int j = 0; j < 8; ++j)
      Apk[idx * 8 + j] = (_Float16)Acat[(kbase + j) * 128 + col];
  }
}

// ---- fuse2: 8-way gather(x1 f16) + GEMM 32->64 + relu -> x2 f16; 4 nodes/block ----
__launch_bounds__(256)
__global__ void k_fuse2(const _Float16* __restrict__ H, const unsigned short* __restrict__ esrc,
                        const int* __restrict__ row_start, const int* __restrict__ bend,
                        const float* __restrict__ dinv,
                        const float* __restrict__ W, const float* __restrict__ bias,
                        _Float16* __restrict__ Y) {
  __shared__ float sZT[32][5];
  __shared__ float sW[32 * 64];
  int t = threadIdx.x;
  int n0 = blockIdx.x * 4;
#pragma unroll
  for (int it = 0; it < 2; ++it) {
    int idx = t + it * 256;
    int kr = idx >> 4, c4 = (idx & 15) * 4;
    *reinterpret_cast<float4*>(&sW[kr * 64 + c4]) =
        *reinterpret_cast<const float4*>(&W[kr * 64 + c4]);
  }
  // 64 lanes/node: fg = sub&7 (half8 group of 32 f16? no: 32 f16 = 4 half8) ->
  // here H rows are x1 (32 f16 = 4 half8): use fg = sub&3, way = sub>>2 (0..15)? keep 8 ways:
  // fg = sub & 3 (4 half8 groups), way = (sub >> 2) & 7, dup = sub >> 5 (2 copies halve edges)
  int node = t >> 6, sub = t & 63, fg = sub & 3, way = (sub >> 2) & 7, dup = sub >> 5;
  int n = n0 + node;
  const half8* H8 = reinterpret_cast<const half8*>(H);
  float acc[8];
#pragma unroll
  for (int j = 0; j < 8; ++j) acc[j] = 0.f;
  if (way == 0 && dup == 0) {
    half8 h = H8[(size_t)n * 4 + fg];
#pragma unroll
    for (int j = 0; j < 8; ++j) acc[j] = 2.f * (float)h[j];
  }
  int end = min(row_start[n + 1], bend[n >> 8]);
  int i = row_start[n] + way + dup * 8;   // 16 ways total (8 ways x 2 dup)
  for (; i < end; i += 16) {
    int s = esrc[i];
    half8 a = H8[(size_t)s * 4 + fg];
#pragma unroll
    for (int j = 0; j < 8; ++j) acc[j] += (float)a[j];
  }
#pragma unroll
  for (int j = 0; j < 8; ++j) {
    acc[j] += __shfl_xor(acc[j], 4);
    acc[j] += __shfl_xor(acc[j], 8);
    acc[j] += __shfl_xor(acc[j], 16);
    acc[j] += __shfl_xor(acc[j], 32);
  }
  if (sub < 4) {  // way==0, dup==0 lanes: fg = sub
    float dv = dinv[n];
#pragma unroll
    for (int j = 0; j < 8; ++j) sZT[fg * 8 + j][node] = dv * acc[j];
  }
  __syncthreads();
  int nd = t >> 6, col = t & 63;
  float a = bias[col];
#pragma unroll
  for (int k = 0; k < 32; ++k) a = fmaf(sZT[k][nd], sW[k * 64 + col], a);
  Y[(size_t)(n0 + nd) * 64 + col] = (_Float16)(dinv[n0 + nd] * fmaxf(a, 0.f));
}

// ---- read half8, unscale by s, repack ----
__device__ inline half8 cvt8h(const _Float16* __restrict__ p, float s) {
  half8 v = *reinterpret_cast<const half8*>(p);
  half8 a;
#pragma unroll
  for (int i = 0; i < 8; ++i) a[i] = (_Float16)(s * (float)v[i]);
  return a;
}

// ------- MFMA decode with in-LDS gather: z3 tile gathered from x2h, then
//         x3 = relu(z3@Wc3+bc3); out = c0 + [x3|x2|x1] @ Acat -------
__launch_bounds__(256)
__global__ void k_decode(const _Float16* __restrict__ X2h, const _Float16* __restrict__ X1h,
                         const unsigned short* __restrict__ esrc,
                         const int* __restrict__ row_start, const int* __restrict__ bend,
                         const float* __restrict__ dinv, const float* __restrict__ rdinv,
                         const half8* __restrict__ W3pk, const half8* __restrict__ Apk,
                         const float* __restrict__ bc3, const float* __restrict__ c0,
                         float* __restrict__ out) {
  __shared__ _Float16 zT[64][72];       // gathered z3 tile (padded: +8 -> 2-way bank alias)
  __shared__ _Float16 sX3[4][16][136];
  int t = threadIdx.x;

  // ---- Phase A: gather z3 rows for this block's 64 nodes ----
  {
    int ln = t >> 2, q = t & 3;          // node-local row, quarter (16 f16 each)
    int n = blockIdx.x * 64 + ln;
    float acc[16];
#pragma unroll
    for (int j = 0; j < 16; ++j) acc[j] = 0.f;
    if (n < NN) {
      const half8* H8 = reinterpret_cast<const half8*>(X2h);
      half8 h0 = H8[(size_t)n * 8 + q * 2];
      half8 h1 = H8[(size_t)n * 8 + q * 2 + 1];
#pragma unroll
      for (int j = 0; j < 8; ++j) {
        acc[j] = 2.f * (float)h0[j];
        acc[8 + j] = 2.f * (float)h1[j];
      }
      int end = min(row_start[n + 1], bend[n >> 8]);
      int i = row_start[n];
      for (; i + 3 < end; i += 4) {
        int s0 = esrc[i], s1 = esrc[i + 1], s2 = esrc[i + 2], s3 = esrc[i + 3];
        half8 a0 = H8[(size_t)s0 * 8 + q * 2], a1 = H8[(size_t)s0 * 8 + q * 2 + 1];
        half8 b0 = H8[(size_t)s1 * 8 + q * 2], b1 = H8[(size_t)s1 * 8 + q * 2 + 1];
        half8 c0v = H8[(size_t)s2 * 8 + q * 2], c1v = H8[(size_t)s2 * 8 + q * 2 + 1];
        half8 d0 = H8[(size_t)s3 * 8 + q * 2], d1 = H8[(size_t)s3 * 8 + q * 2 + 1];
#pragma unroll
        for (int j = 0; j < 8; ++j) {
          acc[j] += ((float)a0[j] + (float)b0[j]) + ((float)c0v[j] + (float)d0[j]);
          acc[8 + j] += ((float)a1[j] + (float)b1[j]) + ((float)c1v[j] + (float)d1[j]);
        }
      }
      for (; i < end; ++i) {
        int s = esrc[i];
        half8 a0 = H8[(size_t)s * 8 + q * 2], a1 = H8[(size_t)s * 8 + q * 2 + 1];
#pragma unroll
        for (int j = 0; j < 8; ++j) {
          acc[j] += (float)a0[j];
          acc[8 + j] += (float)a1[j];
        }
      }
      float dv = dinv[n];
#pragma unroll
      for (int j = 0; j < 16; ++j) acc[j] *= dv;
    }
    half8 z0, z1;
#pragma unroll
    for (int j = 0; j < 8; ++j) {
      z0[j] = (_Float16)acc[j];
      z1[j] = (_Float16)acc[8 + j];
    }
    *reinterpret_cast<half8*>(&zT[ln][q * 16]) = z0;
    *reinterpret_cast<half8*>(&zT[ln][q * 16 + 8]) = z1;
  }
  __syncthreads();

  int w = t >> 6, l = t & 63;
  int m16 = l & 15, g = l >> 4;
  int n0 = blockIdx.x * 64 + w * 16;
  int nrow = n0 + m16;

  f32x4v acc[8];
  // ---- Phase B: x3 = relu(z3 @ Wc3 + bc3), K=64 ----
#pragma unroll
  for (int nb = 0; nb < 8; ++nb) {
    float bv = bc3[nb * 16 + m16];
    acc[nb] = (f32x4v){bv, bv, bv, bv};
  }
#pragma unroll
  for (int kb = 0; kb < 2; ++kb) {
    half8 a = *reinterpret_cast<const half8*>(&zT[w * 16 + m16][kb * 32 + g * 8]);
#pragma unroll
    for (int nb = 0; nb < 8; ++nb) {
      half8 b = W3pk[(kb * 8 + nb) * 64 + l];
      acc[nb] = __builtin_amdgcn_mfma_f32_16x16x32_f16(a, b, acc[nb], 0, 0, 0);
    }
  }
#pragma unroll
  for (int nb = 0; nb < 8; ++nb)
#pragma unroll
    for (int r = 0; r < 4; ++r)
      sX3[w][g * 4 + r][nb * 16 + m16] = (_Float16)fmaxf(acc[nb][r], 0.0f);
  __syncthreads();

  // ---- Phase C: out = c0 + [x3|x2|x1] @ Acat, K=224 ----
  float rd = rdinv[nrow];
#pragma unroll
  for (int nb = 0; nb < 8; ++nb) {
    float cv = c0[nb * 16 + m16];
    acc[nb] = (f32x4v){cv, cv, cv, cv};
  }
#pragma unroll
  for (int kb = 0; kb < 7; ++kb) {
    half8 a;
    if (kb < 4)
      a = *reinterpret_cast<const half8*>(&sX3[w][m16][kb * 32 + g * 8]);
    else if (kb < 6)
      a = cvt8h(X2h + (size_t)nrow * 64 + (kb - 4) * 32 + g * 8, rd);
    else
      a = cvt8h(X1h + (size_t)nrow * 32 + g * 8, rd);
#pragma unroll
    for (int nb = 0; nb < 8; ++nb) {
      half8 b = Apk[(kb * 8 + nb) * 64 + l];
      acc[nb] = __builtin_amdgcn_mfma_f32_16x16x32_f16(a, b, acc[nb], 0, 0, 0);
    }
  }
#pragma unroll
  for (int nb = 0; nb < 8; ++nb)
#pragma unroll
    for (int r = 0; r < 4; ++r) {
      int n = n0 + g * 4 + r;
      if (n < NN) out[(size_t)n * 128 + nb * 16 + m16] = acc[nb][r];
    }
}

extern "C" void kernel_launch(void* const* d_in, const int* in_sizes, int n_in,
                              void* d_out, int out_size, void* d_ws, size_t ws_size,
                              hipStream_t stream) {
  const float* x   = (const float*)d_in[0];
  const int* ei    = (const int*)d_in[1];
  const int* srcv  = ei;
  const int* dstv  = ei + NE;
  const float* w1  = (const float*)d_in[2];
  const float* b1  = (const float*)d_in[3];
  const float* fw1 = (const float*)d_in[4];
  const float* fb1 = (const float*)d_in[5];
  const float* w2  = (const float*)d_in[6];
  const float* b2  = (const float*)d_in[7];
  const float* fw2 = (const float*)d_in[8];
  const float* fb2 = (const float*)d_in[9];
  const float* w3  = (const float*)d_in[10];
  const float* b3  = (const float*)d_in[11];
  const float* fw3 = (const float*)d_in[12];
  const float* fb3 = (const float*)d_in[13];
  const float* wd1 = (const float*)d_in[14];
  const float* bd1 = (const float*)d_in[15];
  const float* wd2 = (const float*)d_in[16];
  const float* bd2 = (const float*)d_in[17];
  const float* wd3 = (const float*)d_in[18];
  const float* bd3 = (const float*)d_in[19];
  const float* ws1 = (const float*)d_in[20];
  const float* bs1 = (const float*)d_in[21];
  const float* ws2 = (const float*)d_in[22];
  const float* bs2 = (const float*)d_in[23];
  const float* wf  = (const float*)d_in[24];
  const float* bf  = (const float*)d_in[25];

  float* fp = (float*)d_ws;
  float* dinv = fp;                         // 50176
  float* rdinv= dinv + 50176;               // 50176
  _Float16* h1h = (_Float16*)(rdinv + 50176);  // 50048*32 halves
  _Float16* x1h = h1h + 1601536;               // 50048*32 halves
  _Float16* x2h = x1h + 1601536;               // 50048*64 halves
  float* Wc2  = (float*)(x2h + 3203072);    // 2048
  float* Wc3  = Wc2 + 2048;                 // 8192
  float* bc1  = Wc3 + 8192;                 // 64
  float* bc2  = bc1 + 64;                   // 64
  float* bc3  = bc2 + 64;                   // 128
  float* G    = bc3 + 128;                  // 16384
  float* Hm   = G + 16384;                  // 16384
  float* A3   = Hm + 16384;                 // 16384 } Acat = A3|A2|A1 [224][128]
  float* A2   = A3 + 16384;                 // 8192  }
  float* A1   = A2 + 8192;                  // 4096  }
  float* c0   = A1 + 4096;                  // 256
  _Float16* W3pk = (_Float16*)(c0 + 256);   // 8192 halves
  _Float16* Apk  = W3pk + 8192;             // 28672 halves
  _Float16* W1pk = Apk + 28672;             // 4096 halves
  unsigned int* epk2 = (unsigned int*)(W1pk + 4096);         // NBLK*CAP u32
  unsigned short* esrc = (unsigned short*)(epk2 + NBLK * CAP); // NBLK*CAP u16
  int* ip     = (int*)(esrc + NBLK * CAP);  // 4B aligned (NBLK*CAP even)
  int* row_start = ip;                      // 50176 (NN+1 used)
  int* bend   = row_start + 50176;          // 256
  int* bcur   = bend + 256;                 // 256

  float* outp = (float*)d_out;

  // ---- CSR build (padded buckets: no histogram, no scan) ----
  hipMemsetAsync(bcur, 0, NBLK * sizeof(int), stream);
  k_A<<<NBLK + 105 + 1, 256, 0, stream>>>(srcv, dstv, bcur, epk2,
                                          wd3, wf, w2, fw2, w3, fw3, b1, fw1, fb1,
                                          b2, fb2, b3, fb3, G, Wc2, Wc3, bc1, bc2, bc3,
                                          w1, W1pk);
  k_B<<<NBLK + 80, 256, 0, stream>>>(epk2, bcur, row_start, bend, dinv, rdinv, esrc,
                                     wd2, G, ws2, Hm, A1);
  // ---- layer-1 MFMA + A32c0 ----
  k_C<<<NG1 + 97, 256, 0, stream>>>(x, (const half8*)W1pk, dinv, h1h,
                                    wd1, ws1, Hm, G, wf, bd1, bs1, bd2, bs2, bd3, bf,
                                    A3, A2, c0);
  // ---- fuse1 + B-frag pack ----
  k_D<<<NF1 + 18, 256, 0, stream>>>(h1h, esrc, row_start, bend, dinv, fw1, bc1, x1h,
                                    Wc3, A3 /*Acat*/, W3pk, Apk);
  k_fuse2<<<NN / 4, 256, 0, stream>>>(x1h, esrc, row_start, bend, dinv, Wc2, bc2, x2h);
  // ---- decode (gathers z3 in-LDS) ----
  k_decode<<<(NN + 63) / 64, 256, 0, stream>>>(x2h, x1h, esrc, row_start, bend, dinv,
                                               rdinv, (const half8*)W3pk,
                                               (const half8*)Apk, bc3, c0, outp);
}

// Round 14
// 141.002 us; speedup vs baseline: 1.0014x; 1.0014x over previous
//
#include <hip/hip_runtime.h>

#define NN 50000
#define NE 800000
#define NBLK 196   // bucket count (256 nodes/bucket); also edge-chunk blocks
#define CAP 5120   // padded slots per bucket (mean 4082, +16 sigma)

typedef _Float16 half8 __attribute__((ext_vector_type(8)));
typedef _Float16 half4 __attribute__((ext_vector_type(4)));
typedef float f32x4v __attribute__((ext_vector_type(4)));

// =================== K_A: padded partition pass 1 + prep1 + w1 pack ===================
__launch_bounds__(256)
__global__ void k_A(const int* __restrict__ srcv, const int* __restrict__ dstv,
                    int* __restrict__ bcur, unsigned int* __restrict__ epk2,
                    const float* __restrict__ wd3, const float* __restrict__ wf,
                    const float* __restrict__ w2, const float* __restrict__ fw2,
                    const float* __restrict__ w3, const float* __restrict__ fw3,
                    const float* __restrict__ b1, const float* __restrict__ fw1,
                    const float* __restrict__ fb1,
                    const float* __restrict__ b2, const float* __restrict__ fb2,
                    const float* __restrict__ b3, const float* __restrict__ fb3,
                    float* __restrict__ G,
                    float* __restrict__ Wc2, float* __restrict__ Wc3,
                    float* __restrict__ bc1, float* __restrict__ bc2,
                    float* __restrict__ bc3,
                    const float* __restrict__ w1, _Float16* __restrict__ W1pk) {
  __shared__ int cnt[256];
  __shared__ int base[256];
  int t = threadIdx.x;
  int b = blockIdx.x;
  if (b < NBLK) {  // ---- part1 (padded buckets, no prior histogram) ----
    int e0 = b * 4096;
    cnt[t] = 0;
    __syncthreads();
    unsigned int pk[16];
    int lo[16], bk[16];
    bool ok[16];
#pragma unroll
    for (int i = 0; i < 16; ++i) {
      int e = e0 + i * 256 + t;
      ok[i] = (e < NE);
      if (ok[i]) {
        int s = srcv[e], d = dstv[e];
        bk[i] = d >> 8;
        pk[i] = (unsigned int)s | ((unsigned int)(d & 255) << 16);
        lo[i] = atomicAdd(&cnt[bk[i]], 1);
      }
    }
    __syncthreads();
    int c = cnt[t];
    if (c > 0) base[t] = atomicAdd(&bcur[t], c);
    __syncthreads();
#pragma unroll
    for (int i = 0; i < 16; ++i)
      if (ok[i]) epk2[(size_t)bk[i] * CAP + base[bk[i]] + lo[i]] = pk[i];
    return;
  }
  if (b < NBLK + 105) {  // ---- prep1: G + Wc2/Wc3/bc1/bc2/bc3 ----
    int id = (b - NBLK) * 256 + t;
    if (id < 16384) {                      // G[c*4+l, k]
      int k = id & 127, r = id >> 7;
      int c = r >> 2, l = r & 3;
      float s = 0.f;
      for (int o = 0; o < 32; ++o) {
        s = fmaf(wd3[c * 64 + o * 2 + 0], wf[(o * 8 + 2 * l + 0) * 128 + k], s);
        s = fmaf(wd3[c * 64 + o * 2 + 1], wf[(o * 8 + 2 * l + 1) * 128 + k], s);
      }
      G[r * 128 + k] = s;
      return;
    }
    int id2 = id - 16384;
    if (id2 < 2048) {                      // Wc2 [32,64]
      int c = id2 >> 6, k = id2 & 63;
      float s = 0.f;
      for (int j = 0; j < 64; ++j) s = fmaf(w2[c * 64 + j], fw2[j * 64 + k], s);
      Wc2[id2] = s;
    } else if (id2 < 10240) {              // Wc3 [64,128]
      int idx = id2 - 2048;
      int c = idx >> 7, k = idx & 127;
      float s = 0.f;
      for (int j = 0; j < 128; ++j) s = fmaf(w3[c * 128 + j], fw3[j * 128 + k], s);
      Wc3[idx] = s;
    } else if (id2 < 10272) {              // bc1 [32]
      int k = id2 - 10240;
      float s = fb1[k];
      for (int j = 0; j < 32; ++j) s = fmaf(b1[j], fw1[j * 32 + k], s);
      bc1[k] = s;
    } else if (id2 < 10336) {              // bc2 [64]
      int k = id2 - 10272;
      float s = fb2[k];
      for (int j = 0; j < 64; ++j) s = fmaf(b2[j], fw2[j * 64 + k], s);
      bc2[k] = s;
    } else if (id2 < 10464) {              // bc3 [128]
      int k = id2 - 10336;
      float s = fb3[k];
      for (int j = 0; j < 128; ++j) s = fmaf(b3[j], fw3[j * 128 + k], s);
      bc3[k] = s;
    }
    return;
  }
  // ---- pack w1 [128][32] fragments: frag (kb,nb) kb<4, nb<2 ----
#pragma unroll
  for (int it = 0; it < 2; ++it) {
    int id = t + it * 256;
    int l = id & 63, f = id >> 6;
    int kb = f >> 1, nb = f & 1;
    int kbase = kb * 32 + ((l >> 4) << 3);
    int col = nb * 16 + (l & 15);
#pragma unroll
    for (int j = 0; j < 8; ++j)
      W1pk[id * 8 + j] = (_Float16)w1[(kbase + j) * 32 + col];
  }
}

// ====== K_B: pass 2 (per-node degree + local scan + place, padded) + prep_HA1 ======
__launch_bounds__(256)
__global__ void k_B(const unsigned int* __restrict__ epk2, const int* __restrict__ bcur,
                    int* __restrict__ row_start, int* __restrict__ bend,
                    float* __restrict__ dinv, float* __restrict__ rdinv,
                    unsigned short* __restrict__ esrc,
                    const float* __restrict__ wd2, const float* __restrict__ G,
                    const float* __restrict__ ws2,
                    float* __restrict__ Hm, float* __restrict__ A1) {
  int t = threadIdx.x;
  int b = blockIdx.x;
  if (b < NBLK) {  // ---- part2 ----
    __shared__ int cnt[256];
    __shared__ int cur[256];
    __shared__ int ss[256];
    int rs0 = b * CAP;
    int count = bcur[b];
    int rs1 = rs0 + count;
    cnt[t] = 0;
    __syncthreads();
    for (int i = rs0 + t; i < rs1; i += 256) {
      unsigned int p = epk2[i];
      atomicAdd(&cnt[(p >> 16) & 255], 1);
    }
    __syncthreads();
    int d = cnt[t];
    ss[t] = d;
    __syncthreads();
    for (int off = 1; off < 256; off <<= 1) {
      int v = (t >= off) ? ss[t - off] : 0;
      __syncthreads();
      ss[t] += v;
      __syncthreads();
    }
    int rs = rs0 + ss[t] - d;
    int node = b * 256 + t;
    if (node < NN) {
      row_start[node] = rs;
      float df = (float)d + 2.0f;
      dinv[node] = rsqrtf(df);
      rdinv[node] = sqrtf(df);
    }
    if (t == 0) bend[b] = rs1;
    if (b == 0 && t == 0) row_start[NN] = NBLK * CAP;
    cur[t] = rs;
    __syncthreads();
    for (int i = rs0 + t; i < rs1; i += 256) {
      unsigned int p = epk2[i];
      int dl = (p >> 16) & 255;
      int tgt = atomicAdd(&cur[dl], 1);
      esrc[tgt] = (unsigned short)(p & 0xFFFFu);
    }
    return;
  }
  int id = (b - NBLK) * 256 + t;
  if (id < 16384) {
    int k = id & 127, r = id >> 7;
    int c = r >> 1, l = r & 1;
    float s = 0.f;
    for (int o = 0; o < 32; ++o) {
      s = fmaf(wd2[c * 64 + o * 2 + 0], G[(o * 4 + 2 * l + 0) * 128 + k], s);
      s = fmaf(wd2[c * 64 + o * 2 + 1], G[(o * 4 + 2 * l + 1) * 128 + k], s);
    }
    Hm[r * 128 + k] = s;
  } else if (id < 16384 + 4096) {
    int idx = id - 16384;
    int k = idx & 127, c = idx >> 7;   // c < 32
    float s = 0.f;
    for (int o = 0; o < 32; ++o) {
      float g = G[(4 * o) * 128 + k] + G[(4 * o + 1) * 128 + k] +
                G[(4 * o + 2) * 128 + k] + G[(4 * o + 3) * 128 + k];
      s = fmaf(ws2[c * 32 + o], g, s);
    }
    A1[c * 128 + k] = s;
  }
}

// ---- convert 8 f32 -> half8 fragment ----
__device__ inline half8 cvt8f(const float* __restrict__ p) {
  float4 u = *reinterpret_cast<const float4*>(p);
  float4 v = *reinterpret_cast<const float4*>(p + 4);
  half8 a;
  a[0] = (_Float16)u.x; a[1] = (_Float16)u.y; a[2] = (_Float16)u.z; a[3] = (_Float16)u.w;
  a[4] = (_Float16)v.x; a[5] = (_Float16)v.y; a[6] = (_Float16)v.z; a[7] = (_Float16)v.w;
  return a;
}

// ============ K_C: layer-1 MFMA (h1' = dinv*(x@w1) -> f16) + prep_A32c0 ============
#define NG1 782  // (NN+63)/64
__launch_bounds__(256)
__global__ void k_C(const float* __restrict__ X, const half8* __restrict__ W1pk,
                    const float* __restrict__ dinv, _Float16* __restrict__ Yh,
                    const float* __restrict__ wd1, const float* __restrict__ ws1,
                    const float* __restrict__ Hm, const float* __restrict__ G,
                    const float* __restrict__ wf,
                    const float* __restrict__ bd1, const float* __restrict__ bs1,
                    const float* __restrict__ bd2, const float* __restrict__ bs2,
                    const float* __restrict__ bd3, const float* __restrict__ bf,
                    float* __restrict__ A3, float* __restrict__ A2,
                    float* __restrict__ c0) {
  int t = threadIdx.x;
  int b = blockIdx.x;
  if (b < NG1) {  // ---- gemm1m ----
    int w = t >> 6, l = t & 63;
    int m16 = l & 15, g = l >> 4;
    int n0 = b * 64 + w * 16;
    int nrow = n0 + m16;
    f32x4v acc[2];
    acc[0] = (f32x4v){0.f, 0.f, 0.f, 0.f};
    acc[1] = (f32x4v){0.f, 0.f, 0.f, 0.f};
#pragma unroll
    for (int kb = 0; kb < 4; ++kb) {
      half8 a = (half8)(_Float16)0.f;
      if (nrow < NN) a = cvt8f(X + (size_t)nrow * 128 + kb * 32 + g * 8);
#pragma unroll
      for (int nb = 0; nb < 2; ++nb)
        acc[nb] = __builtin_amdgcn_mfma_f32_16x16x32_f16(a, W1pk[(kb * 2 + nb) * 64 + l],
                                                         acc[nb], 0, 0, 0);
    }
#pragma unroll
    for (int nb = 0; nb < 2; ++nb)
#pragma unroll
      for (int r = 0; r < 4; ++r) {
        int n = n0 + g * 4 + r;
        if (n < NN)
          Yh[(size_t)n * 32 + nb * 16 + m16] = (_Float16)(dinv[n] * acc[nb][r]);
      }
    return;
  }
  int id = (b - NG1) * 256 + t;
  if (id < 16384) {
    int k = id & 127, c = id >> 7;
    float s = 0.f;
    for (int j = 0; j < 128; ++j) s = fmaf(wd1[c * 128 + j], Hm[j * 128 + k], s);
    A3[c * 128 + k] = s;
  } else if (id < 16384 + 8192) {
    int idx = id - 16384;
    int k = idx & 127, c = idx >> 7;   // c < 64
    float s = 0.f;
    for (int o = 0; o < 64; ++o)
      s = fmaf(ws1[c * 64 + o], Hm[(2 * o) * 128 + k] + Hm[(2 * o + 1) * 128 + k], s);
    A2[c * 128 + k] = s;
  } else if (id < 16384 + 8192 + 128) {
    int k = id - 16384 - 8192;
    float s = bf[k];
    for (int o = 0; o < 64; ++o) {
      float bb = bd1[o] + bs1[o];
      s = fmaf(bb, Hm[(o * 2) * 128 + k] + Hm[(o * 2 + 1) * 128 + k], s);
    }
    for (int o = 0; o < 32; ++o) {
      float bb = bd2[o] + bs2[o];
      float g = G[(o * 4) * 128 + k] + G[(o * 4 + 1) * 128 + k] +
                G[(o * 4 + 2) * 128 + k] + G[(o * 4 + 3) * 128 + k];
      s = fmaf(bb, g, s);
    }
    for (int o = 0; o < 32; ++o) {
      float w8 = 0.f;
      for (int j = 0; j < 8; ++j) w8 += wf[(o * 8 + j) * 128 + k];
      s = fmaf(bd3[o], w8, s);
    }
    c0[k] = s;
  }
}

// ====== K_D: fuse1 (8-way gather h1 + GEMM 32->32 + relu -> x1 f16) + B-frag pack ======
#define NF1 6250  // NN/8
__launch_bounds__(256)
__global__ void k_D(const _Float16* __restrict__ H, const unsigned short* __restrict__ esrc,
                    const int* __restrict__ row_start, const int* __restrict__ bend,
                    const float* __restrict__ dinv,
                    const float* __restrict__ W, const float* __restrict__ bias,
                    _Float16* __restrict__ Y,
                    const float* __restrict__ Wc3, const float* __restrict__ Acat,
                    _Float16* __restrict__ W3pk, _Float16* __restrict__ Apk) {
  int t = threadIdx.x;
  int b = blockIdx.x;
  if (b < NF1) {  // ---- fuse1: 8 nodes/block, 32 lanes/node (fg<4 half8, way<8) ----
    __shared__ float sZT[32][9];
    __shared__ float sW[32 * 32];
    int n0 = b * 8;
    {
      int kr = t >> 3, c4 = (t & 7) * 4;
      *reinterpret_cast<float4*>(&sW[kr * 32 + c4]) =
          *reinterpret_cast<const float4*>(&W[kr * 32 + c4]);
    }
    int node = t >> 5, sub = t & 31, fg = sub & 3, way = sub >> 2;
    int n = n0 + node;
    const half8* H8 = reinterpret_cast<const half8*>(H);
    float acc[8];
#pragma unroll
    for (int j = 0; j < 8; ++j) acc[j] = 0.f;
    if (way == 0) {
      half8 h = H8[(size_t)n * 4 + fg];
#pragma unroll
      for (int j = 0; j < 8; ++j) acc[j] = 2.f * (float)h[j];
    }
    int end = min(row_start[n + 1], bend[n >> 8]);
    int i = row_start[n] + way;
    for (; i + 8 < end; i += 16) {
      int s0 = esrc[i], s1 = esrc[i + 8];
      half8 a = H8[(size_t)s0 * 4 + fg];
      half8 bb = H8[(size_t)s1 * 4 + fg];
#pragma unroll
      for (int j = 0; j < 8; ++j) acc[j] += (float)a[j] + (float)bb[j];
    }
    for (; i < end; i += 8) {
      int s = esrc[i];
      half8 a = H8[(size_t)s * 4 + fg];
#pragma unroll
      for (int j = 0; j < 8; ++j) acc[j] += (float)a[j];
    }
#pragma unroll
    for (int j = 0; j < 8; ++j) {
      acc[j] += __shfl_xor(acc[j], 4);
      acc[j] += __shfl_xor(acc[j], 8);
      acc[j] += __shfl_xor(acc[j], 16);
    }
    if (way == 0) {
      float dv = dinv[n];
#pragma unroll
      for (int j = 0; j < 8; ++j) sZT[fg * 8 + j][node] = dv * acc[j];
    }
    __syncthreads();
    int nd = t >> 5, col = t & 31;
    float a = bias[col];
#pragma unroll
    for (int k = 0; k < 32; ++k) a = fmaf(sZT[k][nd], sW[k * 32 + col], a);
    Y[(size_t)(n0 + nd) * 32 + col] = (_Float16)(dinv[n0 + nd] * fmaxf(a, 0.f));
    return;
  }
  int id = (b - NF1) * 256 + t;
  if (id < 1024) {
    int l = id & 63, nb = (id >> 6) & 7, kb = id >> 9;
    int kbase = kb * 32 + ((l >> 4) << 3);
    int col = nb * 16 + (l & 15);
#pragma unroll
    for (int j = 0; j < 8; ++j)
      W3pk[id * 8 + j] = (_Float16)Wc3[(kbase + j) * 128 + col];
  } else if (id < 1024 + 3584) {
    int idx = id - 1024;
    int l = idx & 63, nb = (idx >> 6) & 7, kb = idx >> 9;
    int kbase = kb * 32 + ((l >> 4) << 3);
    int col = nb * 16 + (l & 15);
#pragma unroll
    for (int j = 0; j < 8; ++j)
      Apk[idx * 8 + j] = (_Float16)Acat[(kbase + j) * 128 + col];
  }
}

// ---- fuse2: 16-way gather(x1 f16) + GEMM 32->64 + relu -> x2 f16; 4 nodes/block ----
__launch_bounds__(256)
__global__ void k_fuse2(const _Float16* __restrict__ H, const unsigned short* __restrict__ esrc,
                        const int* __restrict__ row_start, const int* __restrict__ bend,
                        const float* __restrict__ dinv,
                        const float* __restrict__ W, const float* __restrict__ bias,
                        _Float16* __restrict__ Y) {
  __shared__ float sZT[32][5];
  __shared__ float sW[32 * 64];
  int t = threadIdx.x;
  int n0 = blockIdx.x * 4;
#pragma unroll
  for (int it = 0; it < 2; ++it) {
    int idx = t + it * 256;
    int kr = idx >> 4, c4 = (idx & 15) * 4;
    *reinterpret_cast<float4*>(&sW[kr * 64 + c4]) =
        *reinterpret_cast<const float4*>(&W[kr * 64 + c4]);
  }
  int node = t >> 6, sub = t & 63, fg = sub & 3, way = (sub >> 2) & 7, dup = sub >> 5;
  int n = n0 + node;
  const half8* H8 = reinterpret_cast<const half8*>(H);
  float acc[8];
#pragma unroll
  for (int j = 0; j < 8; ++j) acc[j] = 0.f;
  if (way == 0 && dup == 0) {
    half8 h = H8[(size_t)n * 4 + fg];
#pragma unroll
    for (int j = 0; j < 8; ++j) acc[j] = 2.f * (float)h[j];
  }
  int end = min(row_start[n + 1], bend[n >> 8]);
  int i = row_start[n] + way + dup * 8;   // 16 ways total (8 ways x 2 dup)
  for (; i < end; i += 16) {
    int s = esrc[i];
    half8 a = H8[(size_t)s * 4 + fg];
#pragma unroll
    for (int j = 0; j < 8; ++j) acc[j] += (float)a[j];
  }
#pragma unroll
  for (int j = 0; j < 8; ++j) {
    acc[j] += __shfl_xor(acc[j], 4);
    acc[j] += __shfl_xor(acc[j], 8);
    acc[j] += __shfl_xor(acc[j], 16);
    acc[j] += __shfl_xor(acc[j], 32);
  }
  if (sub < 4) {  // way==0, dup==0 lanes: fg = sub
    float dv = dinv[n];
#pragma unroll
    for (int j = 0; j < 8; ++j) sZT[fg * 8 + j][node] = dv * acc[j];
  }
  __syncthreads();
  int nd = t >> 6, col = t & 63;
  float a = bias[col];
#pragma unroll
  for (int k = 0; k < 32; ++k) a = fmaf(sZT[k][nd], sW[k * 64 + col], a);
  Y[(size_t)(n0 + nd) * 64 + col] = (_Float16)(dinv[n0 + nd] * fmaxf(a, 0.f));
}

// ---- read half8, unscale by s, repack ----
__device__ inline half8 cvt8h(const _Float16* __restrict__ p, float s) {
  half8 v = *reinterpret_cast<const half8*>(p);
  half8 a;
#pragma unroll
  for (int i = 0; i < 8; ++i) a[i] = (_Float16)(s * (float)v[i]);
  return a;
}

// ------- MFMA decode with in-LDS WAY-PARALLEL gather: z3 tile gathered from x2h,
//         then x3 = relu(z3@Wc3+bc3); out = c0 + [x3|x2|x1] @ Acat -------
__launch_bounds__(256)
__global__ void k_decode(const _Float16* __restrict__ X2h, const _Float16* __restrict__ X1h,
                         const unsigned short* __restrict__ esrc,
                         const int* __restrict__ row_start, const int* __restrict__ bend,
                         const float* __restrict__ dinv, const float* __restrict__ rdinv,
                         const half8* __restrict__ W3pk, const half8* __restrict__ Apk,
                         const float* __restrict__ bc3, const float* __restrict__ c0,
                         float* __restrict__ out) {
  __shared__ _Float16 zT[64][72];       // gathered z3 tile (padded +8)
  __shared__ _Float16 sX3[4][16][136];
  int t = threadIdx.x;

  // ---- Phase A: gather z3 rows; 4 threads/node = 2 feature-halves x 2 ways ----
  {
    int ln = t >> 2, q = t & 3;
    int fh = q & 1, way = q >> 1;        // lane bit0 = fh, bit1 = way
    int n = blockIdx.x * 64 + ln;
    float acc[32];
#pragma unroll
    for (int j = 0; j < 32; ++j) acc[j] = 0.f;
    if (n < NN) {
      const half8* H8 = reinterpret_cast<const half8*>(X2h);
      size_t rb = (size_t)n * 8 + fh * 4;
      if (way == 0) {
        half8 h0 = H8[rb], h1 = H8[rb + 1], h2 = H8[rb + 2], h3 = H8[rb + 3];
#pragma unroll
        for (int j = 0; j < 8; ++j) {
          acc[j] = 2.f * (float)h0[j];
          acc[8 + j] = 2.f * (float)h1[j];
          acc[16 + j] = 2.f * (float)h2[j];
          acc[24 + j] = 2.f * (float)h3[j];
        }
      }
      int end = min(row_start[n + 1], bend[n >> 8]);
      int i = row_start[n] + way;
      for (; i + 2 < end; i += 4) {      // 2 edges/iter per way (8 half8 in flight)
        int s0 = esrc[i], s1 = esrc[i + 2];
        size_t r0 = (size_t)s0 * 8 + fh * 4, r1 = (size_t)s1 * 8 + fh * 4;
        half8 a0 = H8[r0], a1 = H8[r0 + 1], a2 = H8[r0 + 2], a3 = H8[r0 + 3];
        half8 b0 = H8[r1], b1 = H8[r1 + 1], b2 = H8[r1 + 2], b3 = H8[r1 + 3];
#pragma unroll
        for (int j = 0; j < 8; ++j) {
          acc[j] += (float)a0[j] + (float)b0[j];
          acc[8 + j] += (float)a1[j] + (float)b1[j];
          acc[16 + j] += (float)a2[j] + (float)b2[j];
          acc[24 + j] += (float)a3[j] + (float)b3[j];
        }
      }
      for (; i < end; i += 2) {
        int s = esrc[i];
        size_t r0 = (size_t)s * 8 + fh * 4;
        half8 a0 = H8[r0], a1 = H8[r0 + 1], a2 = H8[r0 + 2], a3 = H8[r0 + 3];
#pragma unroll
        for (int j = 0; j < 8; ++j) {
          acc[j] += (float)a0[j];
          acc[8 + j] += (float)a1[j];
          acc[16 + j] += (float)a2[j];
          acc[24 + j] += (float)a3[j];
        }
      }
    }
    // merge the two ways (lane XOR 2 = same node, same fh, other way)
#pragma unroll
    for (int j = 0; j < 32; ++j) acc[j] += __shfl_xor(acc[j], 2);
    if (way == 0) {
      float dv = (n < NN) ? dinv[n] : 0.f;
      half8 z0, z1, z2, z3;
#pragma unroll
      for (int j = 0; j < 8; ++j) {
        z0[j] = (_Float16)(dv * acc[j]);
        z1[j] = (_Float16)(dv * acc[8 + j]);
        z2[j] = (_Float16)(dv * acc[16 + j]);
        z3[j] = (_Float16)(dv * acc[24 + j]);
      }
      *reinterpret_cast<half8*>(&zT[ln][fh * 32]) = z0;
      *reinterpret_cast<half8*>(&zT[ln][fh * 32 + 8]) = z1;
      *reinterpret_cast<half8*>(&zT[ln][fh * 32 + 16]) = z2;
      *reinterpret_cast<half8*>(&zT[ln][fh * 32 + 24]) = z3;
    }
  }
  __syncthreads();

  int w = t >> 6, l = t & 63;
  int m16 = l & 15, g = l >> 4;
  int n0 = blockIdx.x * 64 + w * 16;
  int nrow = n0 + m16;

  f32x4v acc[8];
  // ---- Phase B: x3 = relu(z3 @ Wc3 + bc3), K=64 ----
#pragma unroll
  for (int nb = 0; nb < 8; ++nb) {
    float bv = bc3[nb * 16 + m16];
    acc[nb] = (f32x4v){bv, bv, bv, bv};
  }
#pragma unroll
  for (int kb = 0; kb < 2; ++kb) {
    half8 a = *reinterpret_cast<const half8*>(&zT[w * 16 + m16][kb * 32 + g * 8]);
#pragma unroll
    for (int nb = 0; nb < 8; ++nb) {
      half8 b = W3pk[(kb * 8 + nb) * 64 + l];
      acc[nb] = __builtin_amdgcn_mfma_f32_16x16x32_f16(a, b, acc[nb], 0, 0, 0);
    }
  }
#pragma unroll
  for (int nb = 0; nb < 8; ++nb)
#pragma unroll
    for (int r = 0; r < 4; ++r)
      sX3[w][g * 4 + r][nb * 16 + m16] = (_Float16)fmaxf(acc[nb][r], 0.0f);
  __syncthreads();

  // ---- Phase C: out = c0 + [x3|x2|x1] @ Acat, K=224 ----
  float rd = rdinv[nrow];
#pragma unroll
  for (int nb = 0; nb < 8; ++nb) {
    float cv = c0[nb * 16 + m16];
    acc[nb] = (f32x4v){cv, cv, cv, cv};
  }
#pragma unroll
  for (int kb = 0; kb < 7; ++kb) {
    half8 a;
    if (kb < 4)
      a = *reinterpret_cast<const half8*>(&sX3[w][m16][kb * 32 + g * 8]);
    else if (kb < 6)
      a = cvt8h(X2h + (size_t)nrow * 64 + (kb - 4) * 32 + g * 8, rd);
    else
      a = cvt8h(X1h + (size_t)nrow * 32 + g * 8, rd);
#pragma unroll
    for (int nb = 0; nb < 8; ++nb) {
      half8 b = Apk[(kb * 8 + nb) * 64 + l];
      acc[nb] = __builtin_amdgcn_mfma_f32_16x16x32_f16(a, b, acc[nb], 0, 0, 0);
    }
  }
#pragma unroll
  for (int nb = 0; nb < 8; ++nb)
#pragma unroll
    for (int r = 0; r < 4; ++r) {
      int n = n0 + g * 4 + r;
      if (n < NN) out[(size_t)n * 128 + nb * 16 + m16] = acc[nb][r];
    }
}

extern "C" void kernel_launch(void* const* d_in, const int* in_sizes, int n_in,
                              void* d_out, int out_size, void* d_ws, size_t ws_size,
                              hipStream_t stream) {
  const float* x   = (const float*)d_in[0];
  const int* ei    = (const int*)d_in[1];
  const int* srcv  = ei;
  const int* dstv  = ei + NE;
  const float* w1  = (const float*)d_in[2];
  const float* b1  = (const float*)d_in[3];
  const float* fw1 = (const float*)d_in[4];
  const float* fb1 = (const float*)d_in[5];
  const float* w2  = (const float*)d_in[6];
  const float* b2  = (const float*)d_in[7];
  const float* fw2 = (const float*)d_in[8];
  const float* fb2 = (const float*)d_in[9];
  const float* w3  = (const float*)d_in[10];
  const float* b3  = (const float*)d_in[11];
  const float* fw3 = (const float*)d_in[12];
  const float* fb3 = (const float*)d_in[13];
  const float* wd1 = (const float*)d_in[14];
  const float* bd1 = (const float*)d_in[15];
  const float* wd2 = (const float*)d_in[16];
  const float* bd2 = (const float*)d_in[17];
  const float* wd3 = (const float*)d_in[18];
  const float* bd3 = (const float*)d_in[19];
  const float* ws1 = (const float*)d_in[20];
  const float* bs1 = (const float*)d_in[21];
  const float* ws2 = (const float*)d_in[22];
  const float* bs2 = (const float*)d_in[23];
  const float* wf  = (const float*)d_in[24];
  const float* bf  = (const float*)d_in[25];

  float* fp = (float*)d_ws;
  float* dinv = fp;                         // 50176
  float* rdinv= dinv + 50176;               // 50176
  _Float16* h1h = (_Float16*)(rdinv + 50176);  // 50048*32 halves
  _Float16* x1h = h1h + 1601536;               // 50048*32 halves
  _Float16* x2h = x1h + 1601536;               // 50048*64 halves
  float* Wc2  = (float*)(x2h + 3203072);    // 2048
  float* Wc3  = Wc2 + 2048;                 // 8192
  float* bc1  = Wc3 + 8192;                 // 64
  float* bc2  = bc1 + 64;                   // 64
  float* bc3  = bc2 + 64;                   // 128
  float* G    = bc3 + 128;                  // 16384
  float* Hm   = G + 16384;                  // 16384
  float* A3   = Hm + 16384;                 // 16384 } Acat = A3|A2|A1 [224][128]
  float* A2   = A3 + 16384;                 // 8192  }
  float* A1   = A2 + 8192;                  // 4096  }
  float* c0   = A1 + 4096;                  // 256
  _Float16* W3pk = (_Float16*)(c0 + 256);   // 8192 halves
  _Float16* Apk  = W3pk + 8192;             // 28672 halves
  _Float16* W1pk = Apk + 28672;             // 4096 halves
  unsigned int* epk2 = (unsigned int*)(W1pk + 4096);         // NBLK*CAP u32
  unsigned short* esrc = (unsigned short*)(epk2 + NBLK * CAP); // NBLK*CAP u16
  int* ip     = (int*)(esrc + NBLK * CAP);  // 4B aligned (NBLK*CAP even)
  int* row_start = ip;                      // 50176 (NN+1 used)
  int* bend   = row_start + 50176;          // 256
  int* bcur   = bend + 256;                 // 256

  float* outp = (float*)d_out;

  // ---- CSR build (padded buckets: no histogram, no scan) ----
  hipMemsetAsync(bcur, 0, NBLK * sizeof(int), stream);
  k_A<<<NBLK + 105 + 1, 256, 0, stream>>>(srcv, dstv, bcur, epk2,
                                          wd3, wf, w2, fw2, w3, fw3, b1, fw1, fb1,
                                          b2, fb2, b3, fb3, G, Wc2, Wc3, bc1, bc2, bc3,
                                          w1, W1pk);
  k_B<<<NBLK + 80, 256, 0, stream>>>(epk2, bcur, row_start, bend, dinv, rdinv, esrc,
                                     wd2, G, ws2, Hm, A1);
  // ---- layer-1 MFMA + A32c0 ----
  k_C<<<NG1 + 97, 256, 0, stream>>>(x, (const half8*)W1pk, dinv, h1h,
                                    wd1, ws1, Hm, G, wf, bd1, bs1, bd2, bs2, bd3, bf,
                                    A3, A2, c0);
  // ---- fuse1 + B-frag pack ----
  k_D<<<NF1 + 18, 256, 0, stream>>>(h1h, esrc, row_start, bend, dinv, fw1, bc1, x1h,
                                    Wc3, A3 /*Acat*/, W3pk, Apk);
  k_fuse2<<<NN / 4, 256, 0, stream>>>(x1h, esrc, row_start, bend, dinv, Wc2, bc2, x2h);
  // ---- decode (way-parallel in-LDS z3 gather) ----
  k_decode<<<(NN + 63) / 64, 256, 0, stream>>>(x2h, x1h, esrc, row_start, bend, dinv,
                                               rdinv, (const half8*)W3pk,
                                               (const half8*)Apk, bc3, c0, outp);
}